// Round 15
// baseline (1034.621 us; speedup 1.0000x reference)
//
#include <hip/hip_runtime.h>
#include <math.h>

#define NPIX 9216
#define HH 96
#define KSPLIT 24
#define KEYS 384   // 9216/24

// ---------------------------------------------------------------- utilities

__global__ __launch_bounds__(64) void zero_stats_kernel(float* stats) {
    if (threadIdx.x < 16) stats[threadIdx.x] = 0.f;
}

__device__ __forceinline__ void wave_stats_atomic(float s, float s2, float* stats, int tid) {
    #pragma unroll
    for (int off = 32; off > 0; off >>= 1) {
        s  += __shfl_down(s,  off);
        s2 += __shfl_down(s2, off);
    }
    if ((tid & 63) == 0) {
        atomicAdd(&stats[0], s);
        atomicAdd(&stats[1], s2);
    }
}

// ---------------------------------------------------------------- conv3x3 (+ fused LN stats)
// Block: 256 threads = (tx 0..15, ty 0..15). Tile 32 wide x 16 tall, each
// thread 2 pixels in x, CO output channels. Grid (3, 6, Cout/CO).
// LDS: input tile only, [8 ci][18 rows][36 cols] (bank-uniform b64 reads).
// Weights: wave-uniform indices -> scalar s_loads (SMEM port, no LDS).
template<int CIN, int CO>
__global__ __launch_bounds__(256) void conv3x3_t(
        const float* __restrict__ in, const float* __restrict__ w,
        float* __restrict__ out, float* __restrict__ stats) {
    constexpr int STAGES = (CIN + 7) / 8;
    __shared__ float tile[8][18][36];

    const int tid = threadIdx.x;
    const int tx = tid & 15, ty = tid >> 4;
    const int x0 = blockIdx.x * 32, y0 = blockIdx.y * 16;
    const int co0 = blockIdx.z * CO;

    float acc[CO][2];
    #pragma unroll
    for (int j = 0; j < CO; ++j) { acc[j][0] = 0.f; acc[j][1] = 0.f; }

    for (int st = 0; st < STAGES; ++st) {
        __syncthreads();
        // stage 8 input channels of 18x34 halo tile
        for (int i = tid; i < 8 * 18 * 34; i += 256) {
            int ci  = i / (18 * 34);
            int rem = i - ci * (18 * 34);
            int r   = rem / 34;
            int c   = rem - r * 34;
            int cig = st * 8 + ci;
            int gy = y0 + r - 1, gx = x0 + c - 1;
            float v = 0.f;
            if (cig < CIN && gy >= 0 && gy < HH && gx >= 0 && gx < HH)
                v = in[cig * NPIX + gy * HH + gx];
            tile[ci][r][c] = v;
        }
        __syncthreads();

        #pragma unroll
        for (int ci = 0; ci < 8; ++ci) {
            int cig = st * 8 + ci;
            int cw = cig < CIN ? cig : CIN - 1;   // clamped (x0 tile => contributes 0)
            float tv[3][4];
            #pragma unroll
            for (int r = 0; r < 3; ++r) {
                float2 a = *(const float2*)&tile[ci][ty + r][2 * tx];
                float2 b = *(const float2*)&tile[ci][ty + r][2 * tx + 2];
                tv[r][0] = a.x; tv[r][1] = a.y; tv[r][2] = b.x; tv[r][3] = b.y;
            }
            #pragma unroll
            for (int j = 0; j < CO; ++j) {
                const float* wp = w + ((size_t)(co0 + j) * CIN + cw) * 9;
                #pragma unroll
                for (int r = 0; r < 3; ++r) {
                    #pragma unroll
                    for (int d = 0; d < 3; ++d) {
                        float wv = wp[r * 3 + d];    // wave-uniform -> s_load
                        acc[j][0] += wv * tv[r][d];
                        acc[j][1] += wv * tv[r][d + 1];
                    }
                }
            }
        }
    }

    const int oy = y0 + ty, ox = x0 + 2 * tx;
    float s = 0.f, s2 = 0.f;
    #pragma unroll
    for (int j = 0; j < CO; ++j) {
        #pragma unroll
        for (int p = 0; p < 2; ++p) {
            float v = acc[j][p];
            out[(size_t)(co0 + j) * NPIX + oy * HH + ox + p] = v;
            s += v; s2 += v * v;
        }
    }
    wave_stats_atomic(s, s2, stats, tid);
}

// ---------------------------------------------------------------- LN apply + ReLU (float4, in-place)
__global__ __launch_bounds__(256) void ln_apply_relu_kernel(
        float* __restrict__ x, const float* __restrict__ w,
        const float* __restrict__ b, const float* __restrict__ stats,
        int n4, float inv_n) {
    int i = blockIdx.x * 256 + threadIdx.x;
    if (i >= n4) return;
    float m   = stats[0] * inv_n;
    float var = stats[1] * inv_n - m * m;
    float inv = rsqrtf(var + 1e-5f);
    float4 xv = ((const float4*)x)[i];
    float4 wv = ((const float4*)w)[i];
    float4 bv = ((const float4*)b)[i];
    float4 o;
    o.x = fmaxf((xv.x - m) * inv * wv.x + bv.x, 0.f);
    o.y = fmaxf((xv.y - m) * inv * wv.y + bv.y, 0.f);
    o.z = fmaxf((xv.z - m) * inv * wv.z + bv.z, 0.f);
    o.w = fmaxf((xv.w - m) * inv * wv.w + bv.w, 0.f);
    ((float4*)x)[i] = o;
}

// ---------------------------------------------------------------- QKV (1x1, 17->17, bias)
// grid (36, 3): y=0 -> q [c][n], y=1 -> kT [n][20], y=2 -> vT [n][20]
__global__ __launch_bounds__(256) void qkv_kernel(
        const float* __restrict__ h,
        const float* __restrict__ qw, const float* __restrict__ qb,
        const float* __restrict__ kw, const float* __restrict__ kb,
        const float* __restrict__ vw, const float* __restrict__ vb,
        float* __restrict__ q, float* __restrict__ kT, float* __restrict__ vT) {
    int n = blockIdx.x * 256 + threadIdx.x;
    int mode = blockIdx.y;
    const float* w = mode == 0 ? qw : (mode == 1 ? kw : vw);
    const float* b = mode == 0 ? qb : (mode == 1 ? kb : vb);
    float hv[17];
    #pragma unroll
    for (int c = 0; c < 17; ++c) hv[c] = h[c * NPIX + n];
    float o[17];
    #pragma unroll
    for (int co = 0; co < 17; ++co) {
        float s = b[co];
        #pragma unroll
        for (int ci = 0; ci < 17; ++ci) s += w[co * 17 + ci] * hv[ci];
        o[co] = s;
    }
    if (mode == 0) {
        #pragma unroll
        for (int c = 0; c < 17; ++c) q[c * NPIX + n] = o[c];
    } else {
        float* dst = (mode == 1 ? kT : vT);
        #pragma unroll
        for (int c = 0; c < 17; ++c) dst[n * 20 + c] = o[c];
    }
}

// ---------------------------------------------------------------- CAM
__global__ __launch_bounds__(256) void cam_e_kernel(const float* __restrict__ h, float* e) {
    int c = blockIdx.x / 17, d = blockIdx.x - c * 17;
    const float4* hc = (const float4*)(h + c * NPIX);
    const float4* hd = (const float4*)(h + d * NPIX);
    float s = 0.f;
    for (int i = threadIdx.x; i < NPIX / 4; i += 256) {
        float4 a = hc[i], b = hd[i];
        s += a.x * b.x + a.y * b.y + a.z * b.z + a.w * b.w;
    }
    #pragma unroll
    for (int off = 32; off > 0; off >>= 1) s += __shfl_down(s, off);
    __shared__ float red[4];
    int wid = threadIdx.x >> 6;
    if ((threadIdx.x & 63) == 0) red[wid] = s;
    __syncthreads();
    if (threadIdx.x == 0) e[blockIdx.x] = red[0] + red[1] + red[2] + red[3];
}

__global__ __launch_bounds__(64) void cam_softmax_kernel(const float* __restrict__ e,
                                                         float* __restrict__ a) {
    int c = threadIdx.x;
    if (c >= 17) return;
    float rmax = -1e30f, rmin = 1e30f;
    for (int d = 0; d < 17; ++d) {
        float v = e[c * 17 + d];
        rmax = fmaxf(rmax, v);
        rmin = fminf(rmin, v);
    }
    float p[17], sum = 0.f;
    for (int d = 0; d < 17; ++d) {
        p[d] = __expf(rmin - e[c * 17 + d]);
        sum += p[d];
    }
    float inv = 1.f / sum;
    for (int d = 0; d < 17; ++d) a[c * 17 + d] = p[d] * inv;
}

// ---------------------------------------------------------------- PAM flash (no LDS: broadcast loads)
// grid (36, KSPLIT), block 256; thread = one query over this split's keys.
__global__ __launch_bounds__(256) void pam_flash_kernel(
        const float* __restrict__ q, const float* __restrict__ kT,
        const float* __restrict__ vT,
        float* __restrict__ m_part, float* __restrict__ l_part,
        float* __restrict__ o_part) {
    const int qi = blockIdx.x * 256 + threadIdx.x;
    const int sp = blockIdx.y;
    const int k0 = sp * KEYS;

    float qr[17];
    #pragma unroll
    for (int c = 0; c < 17; ++c) qr[c] = q[c * NPIX + qi];

    float mr = -1e30f, lr = 0.f;
    float orr[17];
    #pragma unroll
    for (int c = 0; c < 17; ++c) orr[c] = 0.f;

    #pragma unroll 2
    for (int mm = 0; mm < KEYS; ++mm) {
        const float4* kp = (const float4*)(kT + (size_t)(k0 + mm) * 20);
        float4 ka = kp[0], kb = kp[1], kc = kp[2], kd = kp[3];
        float k16 = kT[(size_t)(k0 + mm) * 20 + 16];
        float s0 = qr[0] * ka.x + qr[1] * ka.y + qr[2] * ka.z + qr[3] * ka.w;
        float s1 = qr[4] * kb.x + qr[5] * kb.y + qr[6] * kb.z + qr[7] * kb.w;
        float s2 = qr[8] * kc.x + qr[9] * kc.y + qr[10] * kc.z + qr[11] * kc.w;
        float s3 = qr[12] * kd.x + qr[13] * kd.y + qr[14] * kd.z + qr[15] * kd.w;
        float s = (s0 + s1) + (s2 + s3) + qr[16] * k16;

        if (s > mr + 8.f) {                 // defer-max: rescale rarely
            float sc = __expf(mr - s);
            lr *= sc;
            #pragma unroll
            for (int c = 0; c < 17; ++c) orr[c] *= sc;
            mr = s;
        }
        float p = __expf(s - mr);
        lr += p;

        const float4* vp = (const float4*)(vT + (size_t)(k0 + mm) * 20);
        float4 va = vp[0], vb = vp[1], vc = vp[2], vd = vp[3];
        float v16 = vT[(size_t)(k0 + mm) * 20 + 16];
        orr[0]  += p * va.x;  orr[1]  += p * va.y;  orr[2]  += p * va.z;  orr[3]  += p * va.w;
        orr[4]  += p * vb.x;  orr[5]  += p * vb.y;  orr[6]  += p * vb.z;  orr[7]  += p * vb.w;
        orr[8]  += p * vc.x;  orr[9]  += p * vc.y;  orr[10] += p * vc.z;  orr[11] += p * vc.w;
        orr[12] += p * vd.x;  orr[13] += p * vd.y;  orr[14] += p * vd.z;  orr[15] += p * vd.w;
        orr[16] += p * v16;
    }

    m_part[sp * NPIX + qi] = mr;
    l_part[sp * NPIX + qi] = lr;
    #pragma unroll
    for (int c = 0; c < 17; ++c)
        o_part[((size_t)sp * 17 + c) * NPIX + qi] = orr[c];
}

// grid (36, 4): c-groups {0..3},{4..7},{8..11},{12..16}
__global__ __launch_bounds__(256) void pam_merge_kernel(
        const float* __restrict__ m_part, const float* __restrict__ l_part,
        const float* __restrict__ o_part, const float* __restrict__ gamma,
        float* __restrict__ pam) {
    const int qi = blockIdx.x * 256 + threadIdx.x;
    const int cg = blockIdx.y;
    const int c_lo = cg * 4;
    const int c_hi = (cg == 3) ? 17 : c_lo + 4;

    float M = -1e30f;
    #pragma unroll
    for (int s = 0; s < KSPLIT; ++s) M = fmaxf(M, m_part[s * NPIX + qi]);
    float wsc[KSPLIT];
    float L = 0.f;
    #pragma unroll
    for (int s = 0; s < KSPLIT; ++s) {
        float wv = __expf(m_part[s * NPIX + qi] - M);
        wsc[s] = wv;
        L += wv * l_part[s * NPIX + qi];
    }
    float invL = gamma[0] / L;
    for (int c = c_lo; c < c_hi; ++c) {
        float acc = 0.f;
        #pragma unroll
        for (int s = 0; s < KSPLIT; ++s)
            acc += wsc[s] * o_part[((size_t)s * 17 + c) * NPIX + qi];
        pam[c * NPIX + qi] = acc * invL;
    }
}

// ---------------------------------------------------------------- y = cam+pam+h ; conv5 ; stats
__global__ __launch_bounds__(256) void y_conv5_kernel(
        const float* __restrict__ h, const float* __restrict__ a,
        const float* __restrict__ cam_gamma, const float* __restrict__ pam,
        const float* __restrict__ w5, float* __restrict__ t5,
        float* __restrict__ stats) {
    int n = blockIdx.x * 256 + threadIdx.x;
    float hv[17], yv[17];
    #pragma unroll
    for (int c = 0; c < 17; ++c) hv[c] = h[c * NPIX + n];
    float g = cam_gamma[0];
    #pragma unroll
    for (int c = 0; c < 17; ++c) {
        float s = 0.f;
        #pragma unroll
        for (int d = 0; d < 17; ++d) s += a[c * 17 + d] * hv[d];
        yv[c] = g * s + pam[c * NPIX + n] + hv[c];
    }
    float s = 0.f, s2 = 0.f;
    #pragma unroll
    for (int co = 0; co < 17; ++co) {
        float t = 0.f;
        #pragma unroll
        for (int ci = 0; ci < 17; ++ci) t += w5[co * 17 + ci] * yv[ci];
        t5[co * NPIX + n] = t;
        s += t; s2 += t * t;
    }
    wave_stats_atomic(s, s2, stats, threadIdx.x);
}

// ---------------------------------------------------------------- ln5+relu ; conv6 -> out
__global__ __launch_bounds__(256) void ln5_conv6_kernel(
        const float* __restrict__ t5, const float* __restrict__ lnw,
        const float* __restrict__ lnb, const float* __restrict__ stats,
        const float* __restrict__ w6, float* __restrict__ out, float inv_n) {
    int n = blockIdx.x * 256 + threadIdx.x;
    float m   = stats[0] * inv_n;
    float var = stats[1] * inv_n - m * m;
    float inv = rsqrtf(var + 1e-5f);
    float act[17];
    #pragma unroll
    for (int c = 0; c < 17; ++c) {
        float t = (t5[c * NPIX + n] - m) * inv * lnw[c * NPIX + n] + lnb[c * NPIX + n];
        act[c] = fmaxf(t, 0.f);
    }
    #pragma unroll
    for (int co = 0; co < 17; ++co) {
        float s = 0.f;
        #pragma unroll
        for (int ci = 0; ci < 17; ++ci) s += w6[co * 17 + ci] * act[ci];
        out[co * NPIX + n] = s;
    }
}

// ---------------------------------------------------------------- launch

extern "C" void kernel_launch(void* const* d_in, const int* in_sizes, int n_in,
                              void* d_out, int out_size, void* d_ws, size_t ws_size,
                              hipStream_t stream) {
    const float* x       = (const float*)d_in[0];
    const float* conv1_w = (const float*)d_in[1];
    const float* ln1_w   = (const float*)d_in[2];
    const float* ln1_b   = (const float*)d_in[3];
    const float* conv2_w = (const float*)d_in[4];
    const float* ln2_w   = (const float*)d_in[5];
    const float* ln2_b   = (const float*)d_in[6];
    const float* conv3_w = (const float*)d_in[7];
    const float* ln3_w   = (const float*)d_in[8];
    const float* ln3_b   = (const float*)d_in[9];
    const float* conv4_w = (const float*)d_in[10];
    const float* ln4_w   = (const float*)d_in[11];
    const float* ln4_b   = (const float*)d_in[12];
    const float* cam_g   = (const float*)d_in[13];
    const float* q_w     = (const float*)d_in[14];
    const float* q_b     = (const float*)d_in[15];
    const float* k_w     = (const float*)d_in[16];
    const float* k_b     = (const float*)d_in[17];
    const float* v_w     = (const float*)d_in[18];
    const float* v_b     = (const float*)d_in[19];
    const float* pam_g   = (const float*)d_in[20];
    const float* conv5_w = (const float*)d_in[21];
    const float* ln5_w   = (const float*)d_in[22];
    const float* ln5_b   = (const float*)d_in[23];
    const float* conv6_w = (const float*)d_in[24];
    float* out = (float*)d_out;

    float* W = (float*)d_ws;
    size_t cur = 0;
    auto alloc = [&](size_t nfloats) {
        float* p = W + cur;
        cur += (nfloats + 15) & ~(size_t)15;   // 16-float align
        return p;
    };
    float* stats  = alloc(16);
    float* h1     = alloc(96 * NPIX);
    float* h2     = alloc(48 * NPIX);
    float* h3     = alloc(48 * NPIX);
    float* h4     = alloc(17 * NPIX);
    float* qbuf   = alloc(17 * NPIX);
    float* kT     = alloc(NPIX * 20);
    float* vT     = alloc(NPIX * 20);
    float* ebuf   = alloc(289);
    float* abuf   = alloc(289);
    float* m_part = alloc(KSPLIT * NPIX);
    float* l_part = alloc(KSPLIT * NPIX);
    float* o_part = alloc((size_t)KSPLIT * 17 * NPIX);
    float* pam    = alloc(17 * NPIX);
    float* t5     = alloc(17 * NPIX);

    dim3 b256(256);

    zero_stats_kernel<<<1, 64, 0, stream>>>(stats);

    // conv1: 237 -> 96 (CO=4)
    conv3x3_t<237, 4><<<dim3(3, 6, 24), b256, 0, stream>>>(x, conv1_w, h1, stats + 0);
    {
        int n = 96 * NPIX;
        ln_apply_relu_kernel<<<(n / 4 + 255) / 256, b256, 0, stream>>>(h1, ln1_w, ln1_b, stats + 0, n / 4, 1.f / n);
    }
    // conv2: 96 -> 48 (CO=2)
    conv3x3_t<96, 2><<<dim3(3, 6, 24), b256, 0, stream>>>(h1, conv2_w, h2, stats + 2);
    {
        int n = 48 * NPIX;
        ln_apply_relu_kernel<<<(n / 4 + 255) / 256, b256, 0, stream>>>(h2, ln2_w, ln2_b, stats + 2, n / 4, 1.f / n);
    }
    // conv3: 48 -> 48 (CO=2)
    conv3x3_t<48, 2><<<dim3(3, 6, 24), b256, 0, stream>>>(h2, conv3_w, h3, stats + 4);
    {
        int n = 48 * NPIX;
        ln_apply_relu_kernel<<<(n / 4 + 255) / 256, b256, 0, stream>>>(h3, ln3_w, ln3_b, stats + 4, n / 4, 1.f / n);
    }
    // conv4: 48 -> 17 (CO=1)
    conv3x3_t<48, 1><<<dim3(3, 6, 17), b256, 0, stream>>>(h3, conv4_w, h4, stats + 6);
    {
        int n = 17 * NPIX;
        ln_apply_relu_kernel<<<(n / 4 + 255) / 256, b256, 0, stream>>>(h4, ln4_w, ln4_b, stats + 6, n / 4, 1.f / n);
    }

    // QKV (q [c][n]; kT/vT [n][20])
    qkv_kernel<<<dim3(36, 3), b256, 0, stream>>>(h4, q_w, q_b, k_w, k_b, v_w, v_b, qbuf, kT, vT);

    // CAM
    cam_e_kernel<<<289, b256, 0, stream>>>(h4, ebuf);
    cam_softmax_kernel<<<1, 64, 0, stream>>>(ebuf, abuf);

    // PAM
    pam_flash_kernel<<<dim3(36, KSPLIT), b256, 0, stream>>>(qbuf, kT, vT, m_part, l_part, o_part);
    pam_merge_kernel<<<dim3(36, 4), b256, 0, stream>>>(m_part, l_part, o_part, pam_g, pam);

    // y = cam+pam+h ; conv5 (+ln5 stats)
    y_conv5_kernel<<<36, b256, 0, stream>>>(h4, abuf, cam_g, pam, conv5_w, t5, stats + 8);
    // ln5+relu ; conv6
    ln5_conv6_kernel<<<36, b256, 0, stream>>>(t5, ln5_w, ln5_b, stats + 8, conv6_w, out, 1.f / (17 * NPIX));
}